// Round 1
// baseline (334.911 us; speedup 1.0000x reference)
//
#include <hip/hip_runtime.h>

constexpr int NB  = 2;     // batch
constexpr int NCI = 4;     // conv input channels
constexpr int NHH = 256;   // H
constexpr int NWW = 256;   // W
constexpr int NCT = 1024;  // conv output channels

// workspace layout (floats)
constexpr int G_OFF   = 0;
constexpr int G_SIZE  = 3 * NB * NCI * NHH * 48;   // 294912  G[m][b][i][h][dx][r]
constexpr int SW1_OFF = G_OFF + G_SIZE;            // 3*16 column sums of W1
constexpr int Q_OFF   = SW1_OFF + 48;
constexpr int QKV_ONE = NB * 4 * NCT * 64;         // 524288
constexpr int K_OFF   = Q_OFF + QKV_ONE;           // k stored transposed [x][o]
constexpr int V_OFF   = K_OFF + QKV_ONE;

__device__ __forceinline__ float sigmoid_f(float v) {
  return __builtin_amdgcn_rcpf(1.0f + __expf(-v));
}

// K1: G[m][b][i][h][dx][r] = sum_w x_pad[b,i,h,w+dx-1] * W1_m[w,r]
// grid: 3*NB*NCI*(NHH/4) + 3, block 64
__global__ __launch_bounds__(64) void k1_G(
    const float* __restrict__ x,
    const float* __restrict__ qW1, const float* __restrict__ kW1,
    const float* __restrict__ vW1, float* __restrict__ ws) {
  const int tid = threadIdx.x;
  const int NBLK = 3 * NB * NCI * (NHH / 4);
  int bid = blockIdx.x;
  if (bid >= NBLK) {  // column sums of W1 (for conv_b term)
    int m = bid - NBLK;
    if (tid < 16) {
      const float* W1 = (m == 0) ? qW1 : (m == 1) ? kW1 : vW1;
      float s = 0.f;
      for (int w = 0; w < 256; ++w) s += W1[w * 16 + tid];
      ws[SW1_OFF + m * 16 + tid] = s;
    }
    return;
  }
  const int m  = bid / (NB * NCI * (NHH / 4));
  int rem      = bid % (NB * NCI * (NHH / 4));
  const int b  = rem / (NCI * (NHH / 4));
  rem          = rem % (NCI * (NHH / 4));
  const int i  = rem / (NHH / 4);
  const int h0 = (rem % (NHH / 4)) * 4;

  const float* W1 = (m == 0) ? qW1 : (m == 1) ? kW1 : vW1;

  __shared__ float W1l[16 * 260];   // [r][w], stride 260 breaks bank aliasing
  __shared__ float xlb[4][260];     // 4 rows, index shifted by +1, zero-padded

  for (int idx4 = tid; idx4 < 1024; idx4 += 64) {   // stage W1^T
    const float4 t = ((const float4*)W1)[idx4];
    const int w = idx4 >> 2, r0 = (idx4 & 3) * 4;
    W1l[(r0 + 0) * 260 + w] = t.x;
    W1l[(r0 + 1) * 260 + w] = t.y;
    W1l[(r0 + 2) * 260 + w] = t.z;
    W1l[(r0 + 3) * 260 + w] = t.w;
  }
  const float* xbase = x + ((size_t)(b * NCI + i) * NHH + h0) * NWW;
  for (int idx = tid; idx < 4 * 256; idx += 64) {
    const int rr = idx >> 8, w = idx & 255;
    xlb[rr][1 + w] = xbase[rr * NWW + w];
  }
  if (tid < 4) {
    xlb[tid][0] = 0.f; xlb[tid][257] = 0.f; xlb[tid][258] = 0.f; xlb[tid][259] = 0.f;
  }
  __syncthreads();

  const int wc = tid >> 4, r = tid & 15;
  const int w0 = wc * 64;
  float* Gw = ws + G_OFF + ((size_t)(m * NB + b) * NCI + i) * NHH * 48;
  #pragma unroll
  for (int rr = 0; rr < 4; ++rr) {
    const float* xl = xlb[rr];
    float a0 = 0.f, a1 = 0.f, a2 = 0.f;
    float4 cur = *(const float4*)&xl[w0];
    #pragma unroll 4
    for (int w = w0; w < w0 + 64; w += 4) {
      const float4 nxt = *(const float4*)&xl[w + 4];
      const float4 w1  = *(const float4*)&W1l[r * 260 + w];
      a0 += w1.x * cur.x + w1.y * cur.y + w1.z * cur.z + w1.w * cur.w;
      a1 += w1.x * cur.y + w1.y * cur.z + w1.z * cur.w + w1.w * nxt.x;
      a2 += w1.x * cur.z + w1.y * cur.w + w1.z * nxt.x + w1.w * nxt.y;
      cur = nxt;
    }
    a0 += __shfl_xor(a0, 16, 64); a0 += __shfl_xor(a0, 32, 64);
    a1 += __shfl_xor(a1, 16, 64); a1 += __shfl_xor(a1, 32, 64);
    a2 += __shfl_xor(a2, 16, 64); a2 += __shfl_xor(a2, 32, 64);
    if (wc == 0) {
      float* g = Gw + (size_t)(h0 + rr) * 48;
      g[r] = a0; g[16 + r] = a1; g[32 + r] = a2;
    }
  }
}

// K2: fused layer1(conv x W1, sigmoid) + layer2(W2, sigmoid) -> q/k/v head layout.
// grid 768 = NB*3*128 (8 channels per block), block 128 = 8 o x 16 r
__global__ __launch_bounds__(128) void k2_mlp(
    const float* __restrict__ conv_w, const float* __restrict__ conv_b,
    const float* __restrict__ qb1, const float* __restrict__ qW2, const float* __restrict__ qb2,
    const float* __restrict__ kb1, const float* __restrict__ kW2, const float* __restrict__ kb2,
    const float* __restrict__ vb1, const float* __restrict__ vW2, const float* __restrict__ vb2,
    float* __restrict__ ws) {
  const int tid = threadIdx.x;
  const int bid = blockIdx.x;
  const int og = bid & 127;
  const int m  = (bid >> 7) % 3;
  const int b  = bid / 384;
  const int o_loc = tid >> 4, r = tid & 15;
  const int o = og * 8 + o_loc;

  const float* b1 = (m == 0) ? qb1 : (m == 1) ? kb1 : vb1;
  const float* W2 = (m == 0) ? qW2 : (m == 1) ? kW2 : vW2;
  const float* b2 = (m == 0) ? qb2 : (m == 1) ? kb2 : vb2;

  __shared__ float Gl[4 * 4 * 16 * 4];  // [slot][i][r][dx(pad4)] rolling rows h-1..h+1
  __shared__ float W2l[256 * 16];

  for (int j = tid; j < 256 * 16; j += 128) W2l[j] = W2[j];
  for (int j = 256 + tid; j < 1024; j += 128) Gl[j] = 0.f;  // slots 1..3 (slot3 = "row -1")

  float cw[36];
  #pragma unroll
  for (int j = 0; j < 36; ++j) cw[j] = conv_w[o * 36 + j];
  const float bias1 = conv_b[o] * ws[SW1_OFF + m * 16 + r] + b1[r];

  const float* Gbase = ws + G_OFF + (size_t)(m * NB + b) * NCI * NHH * 48;

  // row 0 -> slot 0
  for (int j = tid; j < 192; j += 128) {
    const int i = j / 48, rem = j % 48;
    const int dx = rem >> 4, rr = rem & 15;
    Gl[(i * 16 + rr) * 4 + dx] = Gbase[(size_t)i * NHH * 48 + rem];
  }

  float acc[16];
  #pragma unroll
  for (int s = 0; s < 16; ++s) acc[s] = 0.f;

  for (int h = 0; h < 256; ++h) {
    const int h1 = h + 1;
    const int slot1 = h1 & 3;
    for (int j = tid; j < 192; j += 128) {   // prefetch row h+1
      const int i = j / 48, rem = j % 48;
      const int dx = rem >> 4, rr = rem & 15;
      const float val = (h1 < 256) ? Gbase[((size_t)i * NHH + h1) * 48 + rem] : 0.f;
      Gl[((slot1 * 4 + i) * 16 + rr) * 4 + dx] = val;
    }
    __syncthreads();
    float pre = bias1;
    #pragma unroll
    for (int dy = 0; dy < 3; ++dy) {
      const int slot = (h + dy - 1) & 3;
      #pragma unroll
      for (int i = 0; i < 4; ++i) {
        const float4 g = *(const float4*)&Gl[((slot * 4 + i) * 16 + r) * 4];
        pre += cw[i * 9 + dy * 3 + 0] * g.x
             + cw[i * 9 + dy * 3 + 1] * g.y
             + cw[i * 9 + dy * 3 + 2] * g.z;
      }
    }
    const float y1 = sigmoid_f(pre);
    #pragma unroll
    for (int k4 = 0; k4 < 4; ++k4) {
      const float4 wv = *(const float4*)&W2l[h * 16 + k4 * 4];
      acc[k4 * 4 + 0] += y1 * wv.x;
      acc[k4 * 4 + 1] += y1 * wv.y;
      acc[k4 * 4 + 2] += y1 * wv.z;
      acc[k4 * 4 + 3] += y1 * wv.w;
    }
    __syncthreads();
  }

  float* qkv = ws + ((m == 0) ? Q_OFF : (m == 1) ? K_OFF : V_OFF);
  #pragma unroll
  for (int s = 0; s < 16; ++s) {
    const float y2 = sigmoid_f(acc[s] + b2[s]);
    const int n   = (s & 1) * 2 + (r & 1);         // head1*2 + head2
    const int xsp = (s >> 1) * 8 + (r >> 1);       // h_outer*8 + w_outer
    const int bn  = b * 4 + n;
    size_t idx;
    if (m == 1) idx = ((size_t)bn * 64 + xsp) * NCT + o;   // k transposed [x][o]
    else        idx = ((size_t)bn * NCT + o) * 64 + xsp;   // q,v [o][x]
    qkv[idx] = y2;
  }
}

// K3: per (b,n): scores = q k^T * temp over 64-dim, softmax over e, @ v.
// grid 1024 = 8 bn x 128 row-groups (8 rows), block 256.
__global__ __launch_bounds__(256) void k3_attn(
    const float* __restrict__ ws, const float* __restrict__ temp,
    float* __restrict__ out) {
  const int tid = threadIdx.x;
  const int bn = blockIdx.x >> 7;
  const int c0 = (blockIdx.x & 127) * 8;
  const float* q  = ws + Q_OFF + (size_t)bn * NCT * 64;
  const float* kT = ws + K_OFF + (size_t)bn * 64 * NCT;
  const float* v  = ws + V_OFF + (size_t)bn * NCT * 64;
  const float tscale = temp[bn & 3];

  __shared__ float S[8 * 1024];
  __shared__ float ql[64 * 8];   // [d][c]
  __shared__ float lrow[8];

  for (int j = tid; j < 8 * 64; j += 256) {
    const int c = j >> 6, d = j & 63;
    ql[d * 8 + c] = q[(size_t)(c0 + c) * 64 + d];
  }
  __syncthreads();

  { // scores: thread owns e in {tid, tid+256, tid+512, tid+768} x 8 rows
    float acc[32];
    #pragma unroll
    for (int j = 0; j < 32; ++j) acc[j] = 0.f;
    for (int d = 0; d < 64; ++d) {
      const float* kr = kT + (size_t)d * NCT;
      const float kv0 = kr[tid];
      const float kv1 = kr[tid + 256];
      const float kv2 = kr[tid + 512];
      const float kv3 = kr[tid + 768];
      #pragma unroll
      for (int c4 = 0; c4 < 2; ++c4) {
        const float4 qv = *(const float4*)&ql[d * 8 + c4 * 4];
        const float qa[4] = {qv.x, qv.y, qv.z, qv.w};
        #pragma unroll
        for (int jj = 0; jj < 4; ++jj) {
          const int cc = c4 * 4 + jj;
          acc[cc * 4 + 0] += qa[jj] * kv0;
          acc[cc * 4 + 1] += qa[jj] * kv1;
          acc[cc * 4 + 2] += qa[jj] * kv2;
          acc[cc * 4 + 3] += qa[jj] * kv3;
        }
      }
    }
    #pragma unroll
    for (int cc = 0; cc < 8; ++cc) {
      S[cc * 1024 + tid      ] = acc[cc * 4 + 0] * tscale;
      S[cc * 1024 + tid + 256] = acc[cc * 4 + 1] * tscale;
      S[cc * 1024 + tid + 512] = acc[cc * 4 + 2] * tscale;
      S[cc * 1024 + tid + 768] = acc[cc * 4 + 3] * tscale;
    }
  }
  __syncthreads();

  { // softmax per row: 32 lanes per row
    const int c = tid >> 5, l = tid & 31;
    float* row = &S[c * 1024];
    float mx = -1e30f;
    for (int j = l; j < 1024; j += 32) mx = fmaxf(mx, row[j]);
    #pragma unroll
    for (int msk = 1; msk < 32; msk <<= 1) mx = fmaxf(mx, __shfl_xor(mx, msk, 64));
    float sum = 0.f;
    for (int j = l; j < 1024; j += 32) {
      const float p = __expf(row[j] - mx);
      row[j] = p;
      sum += p;
    }
    #pragma unroll
    for (int msk = 1; msk < 32; msk <<= 1) sum += __shfl_xor(sum, msk, 64);
    if (l == 0) lrow[c] = sum;
  }
  __syncthreads();

  { // P @ V, normalize, write with output-reshape mapping
    const int xx = tid & 63, cq = tid >> 6;
    float a0 = 0.f, a1 = 0.f;
    for (int e = 0; e < 1024; e += 4) {
      const float v0 = v[(size_t)(e + 0) * 64 + xx];
      const float v1 = v[(size_t)(e + 1) * 64 + xx];
      const float v2 = v[(size_t)(e + 2) * 64 + xx];
      const float v3 = v[(size_t)(e + 3) * 64 + xx];
      const float4 p0 = *(const float4*)&S[(cq * 2 + 0) * 1024 + e];
      const float4 p1 = *(const float4*)&S[(cq * 2 + 1) * 1024 + e];
      a0 += p0.x * v0 + p0.y * v1 + p0.z * v2 + p0.w * v3;
      a1 += p1.x * v0 + p1.y * v1 + p1.z * v2 + p1.w * v3;
    }
    #pragma unroll
    for (int jr = 0; jr < 2; ++jr) {
      const int c = c0 + cq * 2 + jr;
      const float val = ((jr == 0) ? a0 : a1) / lrow[cq * 2 + jr];
      // att(b,n,c,x) -> out(b, n, h=c>>2, w=64*(c&3)+x)
      out[((size_t)bn * 256 + (c >> 2)) * 256 + 64 * (c & 3) + xx] = val;
    }
  }
}

extern "C" void kernel_launch(void* const* d_in, const int* in_sizes, int n_in,
                              void* d_out, int out_size, void* d_ws, size_t ws_size,
                              hipStream_t stream) {
  (void)in_sizes; (void)n_in; (void)out_size; (void)ws_size;
  const float* x      = (const float*)d_in[0];
  const float* conv_w = (const float*)d_in[1];
  const float* conv_b = (const float*)d_in[2];
  const float* qW1 = (const float*)d_in[3];
  const float* qb1 = (const float*)d_in[4];
  const float* qW2 = (const float*)d_in[5];
  const float* qb2 = (const float*)d_in[6];
  const float* kW1 = (const float*)d_in[7];
  const float* kb1 = (const float*)d_in[8];
  const float* kW2 = (const float*)d_in[9];
  const float* kb2 = (const float*)d_in[10];
  const float* vW1 = (const float*)d_in[11];
  const float* vb1 = (const float*)d_in[12];
  const float* vW2 = (const float*)d_in[13];
  const float* vb2 = (const float*)d_in[14];
  const float* temp = (const float*)d_in[15];
  float* ws  = (float*)d_ws;
  float* out = (float*)d_out;

  k1_G<<<dim3(3 * NB * NCI * (NHH / 4) + 3), dim3(64), 0, stream>>>(x, qW1, kW1, vW1, ws);
  k2_mlp<<<dim3(768), dim3(128), 0, stream>>>(conv_w, conv_b,
      qb1, qW2, qb2, kb1, kW2, kb2, vb1, vW2, vb2, ws);
  k3_attn<<<dim3(1024), dim3(256), 0, stream>>>(ws, temp, out);
}